// Round 12
// baseline (180.569 us; speedup 1.0000x reference)
//
#include <hip/hip_runtime.h>
#include <hip/hip_bf16.h>

#define TT 2048
#define NB 16
#define FD 128
#define ALPHA 0.2f

typedef __attribute__((ext_vector_type(8))) short short8;
typedef __attribute__((ext_vector_type(4))) float f32x4;
typedef __attribute__((ext_vector_type(16))) float f32x16;

static __device__ __forceinline__ unsigned short f2bf(float f) {
    unsigned u = __float_as_uint(f);
    u += 0x7FFF + ((u >> 16) & 1);          // round-to-nearest-even
    return (unsigned short)(u >> 16);
}
static __device__ __forceinline__ unsigned short bfbits(float f) {
    return __builtin_bit_cast(unsigned short, __float2bfloat16(f));  // HW RNE cvt
}

// Kernel 0: WT[f][k] = bf16(W[k][f])  (128x128, tiny)
__global__ __launch_bounds__(256) void k_wt(const float* __restrict__ W,
                                            unsigned short* __restrict__ WT)
{
    int fid = blockIdx.x * 256 + threadIdx.x;   // 4096 float4s
    int k = fid >> 5;
    int f = (fid & 31) << 2;
    float4 w4 = *reinterpret_cast<const float4*>(W + k * FD + f);
    WT[(f + 0) * FD + k] = f2bf(w4.x);
    WT[(f + 1) * FD + k] = f2bf(w4.y);
    WT[(f + 2) * FD + k] = f2bf(w4.z);
    WT[(f + 3) * FD + k] = f2bf(w4.w);
}

// Kernel 1: h = x@W (bf16 MFMA, WT from L2); write hF fragment-linear for
// mfma_f32_32x32x16_bf16: hF[b][j16][n32][lane][e] with
// j = j16*16 + 8*(lane>>5) + e, f = n32*32 + (lane&31).
// Also s1 = h@a1, s2 = h@a2 (fp32).
__global__ __launch_bounds__(256) void k_h(const float* __restrict__ x,
                                           const unsigned short* __restrict__ WT,
                                           const float* __restrict__ a,
                                           unsigned short* __restrict__ hF,
                                           float* __restrict__ s1,
                                           float* __restrict__ s2)
{
    __shared__ unsigned short hs[128][72];   // h-tile transpose staging (18.4 KB)

    const int tid = threadIdx.x;
    const int b  = blockIdx.x >> 5;
    const int t0 = (blockIdx.x & 31) << 6;
    const int w = tid >> 6, l = tid & 63, g = l >> 4, r15 = l & 15;

    const float* xrow = x + ((size_t)(b * TT + t0 + w * 16 + r15)) * FD;

    f32x4 acc[8] = {};

    #pragma unroll
    for (int m = 0; m < 4; ++m) {
        const int koff = m * 32 + g * 8;
        float4 xa = *reinterpret_cast<const float4*>(xrow + koff);
        float4 xb = *reinterpret_cast<const float4*>(xrow + koff + 4);
        short8 af;
        af[0] = (short)f2bf(xa.x); af[1] = (short)f2bf(xa.y);
        af[2] = (short)f2bf(xa.z); af[3] = (short)f2bf(xa.w);
        af[4] = (short)f2bf(xb.x); af[5] = (short)f2bf(xb.y);
        af[6] = (short)f2bf(xb.z); af[7] = (short)f2bf(xb.w);
        #pragma unroll
        for (int n = 0; n < 8; ++n) {
            short8 bfr = *reinterpret_cast<const short8*>(WT + (n * 16 + r15) * FD + koff);
            acc[n] = __builtin_amdgcn_mfma_f32_16x16x32_bf16(af, bfr, acc[n], 0, 0, 0);
        }
    }

    // s1/s2 from fp32 accumulators: lane holds h[t0+w*16+4g+r][16n+r15]
    float p1[4] = {0.f, 0.f, 0.f, 0.f}, p2[4] = {0.f, 0.f, 0.f, 0.f};
    #pragma unroll
    for (int n = 0; n < 8; ++n) {
        float a1v = a[n * 16 + r15];
        float a2v = a[FD + n * 16 + r15];
        #pragma unroll
        for (int r = 0; r < 4; ++r) {
            p1[r] += acc[n][r] * a1v;
            p2[r] += acc[n][r] * a2v;
        }
    }
    #pragma unroll
    for (int r = 0; r < 4; ++r) {
        #pragma unroll
        for (int off = 8; off >= 1; off >>= 1) {
            p1[r] += __shfl_xor(p1[r], off);
            p2[r] += __shfl_xor(p2[r], off);
        }
    }
    if (r15 == 0) {
        const int trow = t0 + w * 16 + g * 4;
        #pragma unroll
        for (int r = 0; r < 4; ++r) {
            s1[b * TT + trow + r] = p1[r];
            s2[b * TT + trow + r] = p2[r];
        }
    }

    // stage h tile (bf16) transposed: hs[f][t_local]
    #pragma unroll
    for (int n = 0; n < 8; ++n)
        #pragma unroll
        for (int r = 0; r < 4; ++r)
            hs[n * 16 + r15][w * 16 + g * 4 + r] = f2bf(acc[n][r]);
    __syncthreads();

    // write fragment-linear hF: 4 j16-tiles x 4 n32 x 64 lanes x 16B = 16KB
    #pragma unroll
    for (int it = 0; it < 4; ++it) {
        int idx = it * 256 + tid;            // 0..1023
        int lp = idx & 63;                   // consumer lane
        int frag = idx >> 6;                 // 0..15
        int n32 = frag & 3, tl = frag >> 2;  // local j16 tile
        int fsrc = n32 * 32 + (lp & 31);
        int tsrc = tl * 16 + (lp >> 5) * 8;
        short8 v = *reinterpret_cast<const short8*>(&hs[fsrc][tsrc]);
        *reinterpret_cast<short8*>(
            hF + (((size_t)(b * 128 + (t0 >> 4) + tl)) * 4 + n32) * 512 + lp * 8) = v;
    }
}

// Kernel 2: single-pass fused mask+softmax+PV, barrier-free main loop.
// Block = 32 i-rows, 4 waves each owning a 512-j quarter x full f=128.
// adj loaded PACK-STYLE: per 64-j chunk, one coalesced dword load per row
// (64 lanes x 4B contiguous), __ballot -> 64-bit j-ordered row mask (SGPR),
// v_perm selects this lane's (h-phase) bytes, (il==r) select captures row
// il's bits into one VGPR. Issue order per chunk: [16 B-frag loads (L2)]
// [32 next-chunk adj loads] -> every in-loop vm wait targets loads issued
// BEFORE the next-chunk adj, so adj always keeps a full chunk in flight
// (~8KB/wave x 8 waves/CU = 64KB/CU). s2 served from LDS (lgkm queue).
__global__ __launch_bounds__(256, 2) void k_att(const int* __restrict__ adj,
                                                const unsigned short* __restrict__ hF,
                                                const float* __restrict__ s1,
                                                const float* __restrict__ s2,
                                                float* __restrict__ out)
{
    __shared__ float s2b[TT];                         // 8 KB
    __shared__ __align__(16) float red[2][32][132];   // 33.8 KB
    __shared__ float dsum[4][32];

    const int tid = threadIdx.x;
    // bijective XCD swizzle: 1024 blocks = 8 XCDs x 128 contiguous
    const int wg = (blockIdx.x & 7) * 128 + (blockIdx.x >> 3);
    const int b  = wg >> 6;
    const int i0 = (wg & 63) << 5;
    const int w = tid >> 6, l = tid & 63;
    const int il = l & 31, h = l >> 5;        // A row, k-half

    // preload this batch's s2 row into LDS (2048 floats, coalesced)
    {
        float4 v0 = *reinterpret_cast<const float4*>(s2 + b * TT + tid * 8);
        float4 v1 = *reinterpret_cast<const float4*>(s2 + b * TT + tid * 8 + 4);
        *reinterpret_cast<float4*>(&s2b[tid * 8])     = v0;
        *reinterpret_cast<float4*>(&s2b[tid * 8 + 4]) = v1;
    }
    const float s1v = s1[b * TT + i0 + il];
    __syncthreads();

    const int jbeg = w * (TT / 4);
    const int* aw = adj + ((size_t)(b * TT + i0)) * TT + jbeg + l;
    const unsigned short* hfp = hF + ((size_t)(b * 128 + (jbeg >> 4))) * 4 * 512 + l * 8;
    const unsigned selH = h ? 0x07050301u : 0x06040200u;   // u64 bytes {2t+h}
    const float* s2w = &s2b[jbeg + h * 8];

    f32x16 acc[4] = {};
    float rsum = 0.f;

    int sA[32], sB[32];                       // adj stage, double-buffered
    #pragma unroll
    for (int r = 0; r < 32; ++r)
        sA[r] = aw[(size_t)r * TT];           // chunk 0

    auto chunk = [&](const int c, int (&stC)[32], int (&stN)[32]) {
        // 1) B-fragments for this chunk's 4 steps (L2, issued before adj)
        short8 bbC[4][4];
        #pragma unroll
        for (int s = 0; s < 4; ++s)
            #pragma unroll
            for (int n = 0; n < 4; ++n)
                bbC[s][n] = *reinterpret_cast<const short8*>(
                    hfp + (size_t)((c * 4 + s) * 4 + n) * 512);
        // 2) next chunk's adj (youngest in queue -> never force-retired)
        if (c < 7) {
            #pragma unroll
            for (int r = 0; r < 32; ++r)
                stN[r] = aw[(size_t)r * TT + (c + 1) * 64];
        }
        // 3) capture this lane's bits for chunk c (waits only on stC)
        unsigned bits = 0;
        #pragma unroll
        for (int r = 0; r < 32; ++r) {
            unsigned long long m = __ballot(stC[r] != 0);          // j-ordered
            unsigned pm = __builtin_amdgcn_perm((unsigned)(m >> 32),
                                                (unsigned)m, selH);
            bits = (il == r) ? pm : bits;
        }
        // 4) 4 MFMA steps of 16 j
        #pragma unroll
        for (int s = 0; s < 4; ++s) {
            const int T = c * 4 + s;
            const unsigned bt = (bits >> (s * 8)) & 0xffu;
            float4 sa = *reinterpret_cast<const float4*>(&s2w[T * 16]);
            float4 sb = *reinterpret_cast<const float4*>(&s2w[T * 16 + 4]);
            float csf[8] = {sa.x, sa.y, sa.z, sa.w, sb.x, sb.y, sb.z, sb.w};
            float pv[8];
            #pragma unroll
            for (int e = 0; e < 8; ++e) {
                float sc = s1v + csf[e];
                sc = fmaxf(sc, ALPHA * sc);                  // leaky_relu
                float p = ((int)(bt << (31 - e)) < 0) ? __expf(sc) : 0.f;
                rsum += p;                                   // denom (unrounded)
                pv[e] = p;
            }
            short8 af;
            #pragma unroll
            for (int e = 0; e < 8; ++e)
                af[e] = (short)bfbits(pv[e]);                // HW RNE cvt
            #pragma unroll
            for (int n = 0; n < 4; ++n)
                acc[n] = __builtin_amdgcn_mfma_f32_32x32x16_bf16(af, bbC[s][n],
                                                                 acc[n], 0, 0, 0);
        }
    };

    #pragma unroll
    for (int cc = 0; cc < 4; ++cc) {
        chunk(2 * cc,     sA, sB);
        chunk(2 * cc + 1, sB, sA);
    }

    // quarter row-sums: combine the two k-halves, store per-wave partials
    rsum += __shfl_xor(rsum, 32);
    if (l < 32) dsum[w][l] = rsum;

    // two-step LDS reduction of the 4 wave-partial accumulators
    if (w < 2) {
        #pragma unroll
        for (int n = 0; n < 4; ++n)
            #pragma unroll
            for (int r = 0; r < 16; ++r) {
                int irow = (r & 3) + 8 * (r >> 2) + 4 * h;
                red[w][irow][n * 32 + il] = acc[n][r];
            }
    }
    __syncthreads();
    if (w >= 2) {
        #pragma unroll
        for (int n = 0; n < 4; ++n)
            #pragma unroll
            for (int r = 0; r < 16; ++r) {
                int irow = (r & 3) + 8 * (r >> 2) + 4 * h;
                red[w - 2][irow][n * 32 + il] += acc[n][r];
            }
    }
    __syncthreads();

    // epilogue: 32 rows x 128 cols = 1024 float4 over 256 threads
    #pragma unroll
    for (int it = 0; it < 4; ++it) {
        int e = it * 256 + tid;
        int row = e >> 5;
        int c4 = (e & 31) << 2;
        float4 v0 = *reinterpret_cast<const float4*>(&red[0][row][c4]);
        float4 v1 = *reinterpret_cast<const float4*>(&red[1][row][c4]);
        float dn = dsum[0][row] + dsum[1][row] + dsum[2][row] + dsum[3][row];
        float ri = 1.0f / dn;
        float4 o;
        o.x = (v0.x + v1.x) * ri;
        o.y = (v0.y + v1.y) * ri;
        o.z = (v0.z + v1.z) * ri;
        o.w = (v0.w + v1.w) * ri;
        *reinterpret_cast<float4*>(out + ((size_t)(b * TT + i0 + row)) * FD + c4) = o;
    }
}

extern "C" void kernel_launch(void* const* d_in, const int* in_sizes, int n_in,
                              void* d_out, int out_size, void* d_ws, size_t ws_size,
                              hipStream_t stream)
{
    const float* x  = (const float*)d_in[0];
    const int* adj  = (const int*)d_in[1];
    const float* W  = (const float*)d_in[2];
    const float* a  = (const float*)d_in[3];
    float* out = (float*)d_out;

    unsigned short* hF = (unsigned short*)d_ws;                       // 8 MB bf16 (fragment-linear)
    float* s1 = (float*)((char*)d_ws + (size_t)NB * FD * TT * 2);
    float* s2 = s1 + NB * TT;
    unsigned short* WT = (unsigned short*)(s2 + NB * TT);             // 32 KB

    k_wt <<<16, 256, 0, stream>>>(W, WT);
    k_h  <<<NB * (TT / 64), 256, 0, stream>>>(x, WT, a, hF, s1, s2);
    k_att<<<NB * (TT / 32), 256, 0, stream>>>(adj, hF, s1, s2, out);
}

// Round 13
// 110.757 us; speedup vs baseline: 1.6303x; 1.6303x over previous
//
#include <hip/hip_runtime.h>
#include <hip/hip_bf16.h>

#define TT 2048
#define NB 16
#define FD 128
#define ALPHA 0.2f

typedef __attribute__((ext_vector_type(8))) short short8;
typedef __attribute__((ext_vector_type(4))) float f32x4;
typedef __attribute__((ext_vector_type(16))) float f32x16;

static __device__ __forceinline__ unsigned short f2bf(float f) {
    unsigned u = __float_as_uint(f);
    u += 0x7FFF + ((u >> 16) & 1);          // round-to-nearest-even
    return (unsigned short)(u >> 16);
}
static __device__ __forceinline__ unsigned short bfbits(float f) {
    return __builtin_bit_cast(unsigned short, __float2bfloat16(f));  // HW RNE cvt
}

// Kernel 0: WT[f][k] = bf16(W[k][f])  (128x128, tiny)
__global__ __launch_bounds__(256) void k_wt(const float* __restrict__ W,
                                            unsigned short* __restrict__ WT)
{
    int fid = blockIdx.x * 256 + threadIdx.x;   // 4096 float4s
    int k = fid >> 5;
    int f = (fid & 31) << 2;
    float4 w4 = *reinterpret_cast<const float4*>(W + k * FD + f);
    WT[(f + 0) * FD + k] = f2bf(w4.x);
    WT[(f + 1) * FD + k] = f2bf(w4.y);
    WT[(f + 2) * FD + k] = f2bf(w4.z);
    WT[(f + 3) * FD + k] = f2bf(w4.w);
}

// Kernel 1: h = x@W (bf16 MFMA, WT from L2); write hF fragment-linear for
// mfma_f32_32x32x16_bf16: hF[b][j16][n32][lane][e] with
// j = j16*16 + 8*(lane>>5) + e, f = n32*32 + (lane&31).
// Also s1 = h@a1, s2 = h@a2 (fp32).
__global__ __launch_bounds__(256) void k_h(const float* __restrict__ x,
                                           const unsigned short* __restrict__ WT,
                                           const float* __restrict__ a,
                                           unsigned short* __restrict__ hF,
                                           float* __restrict__ s1,
                                           float* __restrict__ s2)
{
    __shared__ unsigned short hs[128][72];   // h-tile transpose staging (18.4 KB)

    const int tid = threadIdx.x;
    const int b  = blockIdx.x >> 5;
    const int t0 = (blockIdx.x & 31) << 6;
    const int w = tid >> 6, l = tid & 63, g = l >> 4, r15 = l & 15;

    const float* xrow = x + ((size_t)(b * TT + t0 + w * 16 + r15)) * FD;

    f32x4 acc[8] = {};

    #pragma unroll
    for (int m = 0; m < 4; ++m) {
        const int koff = m * 32 + g * 8;
        float4 xa = *reinterpret_cast<const float4*>(xrow + koff);
        float4 xb = *reinterpret_cast<const float4*>(xrow + koff + 4);
        short8 af;
        af[0] = (short)f2bf(xa.x); af[1] = (short)f2bf(xa.y);
        af[2] = (short)f2bf(xa.z); af[3] = (short)f2bf(xa.w);
        af[4] = (short)f2bf(xb.x); af[5] = (short)f2bf(xb.y);
        af[6] = (short)f2bf(xb.z); af[7] = (short)f2bf(xb.w);
        #pragma unroll
        for (int n = 0; n < 8; ++n) {
            short8 bfr = *reinterpret_cast<const short8*>(WT + (n * 16 + r15) * FD + koff);
            acc[n] = __builtin_amdgcn_mfma_f32_16x16x32_bf16(af, bfr, acc[n], 0, 0, 0);
        }
    }

    // s1/s2 from fp32 accumulators: lane holds h[t0+w*16+4g+r][16n+r15]
    float p1[4] = {0.f, 0.f, 0.f, 0.f}, p2[4] = {0.f, 0.f, 0.f, 0.f};
    #pragma unroll
    for (int n = 0; n < 8; ++n) {
        float a1v = a[n * 16 + r15];
        float a2v = a[FD + n * 16 + r15];
        #pragma unroll
        for (int r = 0; r < 4; ++r) {
            p1[r] += acc[n][r] * a1v;
            p2[r] += acc[n][r] * a2v;
        }
    }
    #pragma unroll
    for (int r = 0; r < 4; ++r) {
        #pragma unroll
        for (int off = 8; off >= 1; off >>= 1) {
            p1[r] += __shfl_xor(p1[r], off);
            p2[r] += __shfl_xor(p2[r], off);
        }
    }
    if (r15 == 0) {
        const int trow = t0 + w * 16 + g * 4;
        #pragma unroll
        for (int r = 0; r < 4; ++r) {
            s1[b * TT + trow + r] = p1[r];
            s2[b * TT + trow + r] = p2[r];
        }
    }

    // stage h tile (bf16) transposed: hs[f][t_local]
    #pragma unroll
    for (int n = 0; n < 8; ++n)
        #pragma unroll
        for (int r = 0; r < 4; ++r)
            hs[n * 16 + r15][w * 16 + g * 4 + r] = f2bf(acc[n][r]);
    __syncthreads();

    // write fragment-linear hF: 4 j16-tiles x 4 n32 x 64 lanes x 16B = 16KB
    #pragma unroll
    for (int it = 0; it < 4; ++it) {
        int idx = it * 256 + tid;            // 0..1023
        int lp = idx & 63;                   // consumer lane
        int frag = idx >> 6;                 // 0..15
        int n32 = frag & 3, tl = frag >> 2;  // local j16 tile
        int fsrc = n32 * 32 + (lp & 31);
        int tsrc = tl * 16 + (lp >> 5) * 8;
        short8 v = *reinterpret_cast<const short8*>(&hs[fsrc][tsrc]);
        *reinterpret_cast<short8*>(
            hF + (((size_t)(b * 128 + (t0 >> 4) + tl)) * 4 + n32) * 512 + lp * 8) = v;
    }
}

// Kernel 2: single-pass fused mask+softmax+PV, barrier-free main loop.
// Block = 32 i-rows, 4 waves each owning a 512-j quarter x full f=128.
// Per 64-j chunk: (1) ballots consume the SINGLE 32-reg adj stage (oldest in
// vm queue - waits on nothing younger); (2) issue this chunk's 16 B-frag
// loads (L2); (3) issue next chunk's 32 adj loads into the SAME stage regs
// (youngest in queue); (4) 4x softmax+MFMA steps - MFMA waits on the B-frags,
// which were issued BEFORE the adj refill, so in-order vmcnt retirement never
// forces the adj stream to drain. Slim register budget (~190: acc 64 +
// stage 32 + bbC 64 + misc) to avoid R12's scratch spill.
__global__ __launch_bounds__(256, 2) void k_att(const int* __restrict__ adj,
                                                const unsigned short* __restrict__ hF,
                                                const float* __restrict__ s1,
                                                const float* __restrict__ s2,
                                                float* __restrict__ out)
{
    __shared__ float s2b[TT];                         // 8 KB
    __shared__ __align__(16) float red[2][32][132];   // 33.8 KB
    __shared__ float dsum[4][32];

    const int tid = threadIdx.x;
    // bijective XCD swizzle: 1024 blocks = 8 XCDs x 128 contiguous
    const int wg = (blockIdx.x & 7) * 128 + (blockIdx.x >> 3);
    const int b  = wg >> 6;
    const int i0 = (wg & 63) << 5;
    const int w = tid >> 6, l = tid & 63;
    const int il = l & 31, h = l >> 5;        // A row, k-half

    // preload this batch's s2 row into LDS (2048 floats, coalesced)
    {
        float4 v0 = *reinterpret_cast<const float4*>(s2 + b * TT + tid * 8);
        float4 v1 = *reinterpret_cast<const float4*>(s2 + b * TT + tid * 8 + 4);
        *reinterpret_cast<float4*>(&s2b[tid * 8])     = v0;
        *reinterpret_cast<float4*>(&s2b[tid * 8 + 4]) = v1;
    }
    const float s1v = s1[b * TT + i0 + il];
    __syncthreads();

    const int jbeg = w * (TT / 4);
    const int* aw = adj + ((size_t)(b * TT + i0)) * TT + jbeg + l;
    const unsigned short* hfp = hF + ((size_t)(b * 128 + (jbeg >> 4))) * 4 * 512 + l * 8;
    const unsigned selH = h ? 0x07050301u : 0x06040200u;   // u64 bytes {2t+h}
    const float* s2w = &s2b[jbeg + h * 8];

    f32x16 acc[4] = {};
    float rsum = 0.f;

    int st[32];                               // SINGLE adj stage (32 VGPR)
    #pragma unroll
    for (int r = 0; r < 32; ++r)
        st[r] = aw[(size_t)r * TT];           // chunk 0

    for (int c = 0; c < 8; ++c) {             // 8 chunks of 64 j
        // (1) capture this lane's bits for chunk c (st is oldest in vm queue)
        unsigned bits = 0;
        #pragma unroll
        for (int r = 0; r < 32; ++r) {
            unsigned long long m = __ballot(st[r] != 0);           // j-ordered
            unsigned pm = __builtin_amdgcn_perm((unsigned)(m >> 32),
                                                (unsigned)m, selH);
            bits = (il == r) ? pm : bits;
        }
        // (2) this chunk's B-fragments (L2) — issued BEFORE the adj refill
        short8 bbC[4][4];
        #pragma unroll
        for (int s = 0; s < 4; ++s)
            #pragma unroll
            for (int n = 0; n < 4; ++n)
                bbC[s][n] = *reinterpret_cast<const short8*>(
                    hfp + (size_t)((c * 4 + s) * 4 + n) * 512);
        // (3) refill stage with next chunk's adj (youngest in queue)
        if (c < 7) {
            #pragma unroll
            for (int r = 0; r < 32; ++r)
                st[r] = aw[(size_t)r * TT + (c + 1) * 64];
        }
        // (4) 4 MFMA steps of 16 j — waits target bbC only
        #pragma unroll
        for (int s = 0; s < 4; ++s) {
            const unsigned bt = (bits >> (s * 8)) & 0xffu;
            float4 sa = *reinterpret_cast<const float4*>(&s2w[(c * 4 + s) * 16]);
            float4 sb = *reinterpret_cast<const float4*>(&s2w[(c * 4 + s) * 16 + 4]);
            float csf[8] = {sa.x, sa.y, sa.z, sa.w, sb.x, sb.y, sb.z, sb.w};
            float pv[8];
            #pragma unroll
            for (int e = 0; e < 8; ++e) {
                float sc = s1v + csf[e];
                sc = fmaxf(sc, ALPHA * sc);                  // leaky_relu
                float p = ((int)(bt << (31 - e)) < 0) ? __expf(sc) : 0.f;
                rsum += p;                                   // denom (unrounded)
                pv[e] = p;
            }
            short8 af;
            #pragma unroll
            for (int e = 0; e < 8; ++e)
                af[e] = (short)bfbits(pv[e]);                // HW RNE cvt
            #pragma unroll
            for (int n = 0; n < 4; ++n)
                acc[n] = __builtin_amdgcn_mfma_f32_32x32x16_bf16(af, bbC[s][n],
                                                                 acc[n], 0, 0, 0);
        }
    }

    // quarter row-sums: combine the two k-halves, store per-wave partials
    rsum += __shfl_xor(rsum, 32);
    if (l < 32) dsum[w][l] = rsum;

    // two-step LDS reduction of the 4 wave-partial accumulators
    if (w < 2) {
        #pragma unroll
        for (int n = 0; n < 4; ++n)
            #pragma unroll
            for (int r = 0; r < 16; ++r) {
                int irow = (r & 3) + 8 * (r >> 2) + 4 * h;
                red[w][irow][n * 32 + il] = acc[n][r];
            }
    }
    __syncthreads();
    if (w >= 2) {
        #pragma unroll
        for (int n = 0; n < 4; ++n)
            #pragma unroll
            for (int r = 0; r < 16; ++r) {
                int irow = (r & 3) + 8 * (r >> 2) + 4 * h;
                red[w - 2][irow][n * 32 + il] += acc[n][r];
            }
    }
    __syncthreads();

    // epilogue: 32 rows x 128 cols = 1024 float4 over 256 threads
    #pragma unroll
    for (int it = 0; it < 4; ++it) {
        int e = it * 256 + tid;
        int row = e >> 5;
        int c4 = (e & 31) << 2;
        float4 v0 = *reinterpret_cast<const float4*>(&red[0][row][c4]);
        float4 v1 = *reinterpret_cast<const float4*>(&red[1][row][c4]);
        float dn = dsum[0][row] + dsum[1][row] + dsum[2][row] + dsum[3][row];
        float ri = 1.0f / dn;
        float4 o;
        o.x = (v0.x + v1.x) * ri;
        o.y = (v0.y + v1.y) * ri;
        o.z = (v0.z + v1.z) * ri;
        o.w = (v0.w + v1.w) * ri;
        *reinterpret_cast<float4*>(out + ((size_t)(b * TT + i0 + row)) * FD + c4) = o;
    }
}

extern "C" void kernel_launch(void* const* d_in, const int* in_sizes, int n_in,
                              void* d_out, int out_size, void* d_ws, size_t ws_size,
                              hipStream_t stream)
{
    const float* x  = (const float*)d_in[0];
    const int* adj  = (const int*)d_in[1];
    const float* W  = (const float*)d_in[2];
    const float* a  = (const float*)d_in[3];
    float* out = (float*)d_out;

    unsigned short* hF = (unsigned short*)d_ws;                       // 8 MB bf16 (fragment-linear)
    float* s1 = (float*)((char*)d_ws + (size_t)NB * FD * TT * 2);
    float* s2 = s1 + NB * TT;
    unsigned short* WT = (unsigned short*)(s2 + NB * TT);             // 32 KB

    k_wt <<<16, 256, 0, stream>>>(W, WT);
    k_h  <<<NB * (TT / 64), 256, 0, stream>>>(x, WT, a, hF, s1, s2);
    k_att<<<NB * (TT / 32), 256, 0, stream>>>(adj, hF, s1, s2, out);
}

// Round 14
// 106.619 us; speedup vs baseline: 1.6936x; 1.0388x over previous
//
#include <hip/hip_runtime.h>
#include <hip/hip_bf16.h>

#define TT 2048
#define NB 16
#define FD 128
#define ALPHA 0.2f

typedef __attribute__((ext_vector_type(8))) short short8;
typedef __attribute__((ext_vector_type(4))) float f32x4;
typedef __attribute__((ext_vector_type(16))) float f32x16;

static __device__ __forceinline__ unsigned short f2bf(float f) {
    unsigned u = __float_as_uint(f);
    u += 0x7FFF + ((u >> 16) & 1);          // round-to-nearest-even
    return (unsigned short)(u >> 16);
}
static __device__ __forceinline__ unsigned short bfbits(float f) {
    return __builtin_bit_cast(unsigned short, __float2bfloat16(f));  // HW RNE cvt
}

// Kernel P: arithmetic bitmask pack, 256 MB -> 8 MB, pure stream.
// Lane l loads int4 (wave = 1 KB contiguous); nibble via min(,1) OR-shifts;
// __shfl_xor(1) pairs even/odd nibbles into a byte; even lanes write 32
// contiguous bytes/wave. Layout: bm[row*256 + k] bit e = adj[row][8k+e]!=0.
__global__ __launch_bounds__(256) void k_pack(const int* __restrict__ adj,
                                              unsigned char* __restrict__ bm)
{
    const int tid = threadIdx.x;
    const int w = tid >> 6, l = tid & 63;
    const int row = blockIdx.x * 4 + w;          // 32768 rows
    const int* ap = adj + (size_t)row * TT + l * 4;
    unsigned char* op = bm + (size_t)row * 256;

    #pragma unroll
    for (int rd = 0; rd < 8; ++rd) {             // 256 j per wave-round
        int4 q = *reinterpret_cast<const int4*>(ap + rd * 256);
        unsigned n =  min((unsigned)q.x, 1u)
                   | (min((unsigned)q.y, 1u) << 1)
                   | (min((unsigned)q.z, 1u) << 2)
                   | (min((unsigned)q.w, 1u) << 3);
        unsigned pn = (unsigned)__shfl_xor((int)n, 1);
        if ((l & 1) == 0)
            op[rd * 32 + (l >> 1)] = (unsigned char)(n | (pn << 4));
    }
}

// Kernel 0: WT[f][k] = bf16(W[k][f])  (128x128, tiny)
__global__ __launch_bounds__(256) void k_wt(const float* __restrict__ W,
                                            unsigned short* __restrict__ WT)
{
    int fid = blockIdx.x * 256 + threadIdx.x;   // 4096 float4s
    int k = fid >> 5;
    int f = (fid & 31) << 2;
    float4 w4 = *reinterpret_cast<const float4*>(W + k * FD + f);
    WT[(f + 0) * FD + k] = f2bf(w4.x);
    WT[(f + 1) * FD + k] = f2bf(w4.y);
    WT[(f + 2) * FD + k] = f2bf(w4.z);
    WT[(f + 3) * FD + k] = f2bf(w4.w);
}

// Kernel 1: h = x@W (bf16 MFMA, WT from L2); write hF fragment-linear for
// mfma_f32_32x32x16_bf16: hF[b][j16][n32][lane][e] with
// j = j16*16 + 8*(lane>>5) + e, f = n32*32 + (lane&31).
// Also s1 = h@a1, s2 = h@a2 (fp32).
__global__ __launch_bounds__(256) void k_h(const float* __restrict__ x,
                                           const unsigned short* __restrict__ WT,
                                           const float* __restrict__ a,
                                           unsigned short* __restrict__ hF,
                                           float* __restrict__ s1,
                                           float* __restrict__ s2)
{
    __shared__ unsigned short hs[128][72];   // h-tile transpose staging (18.4 KB)

    const int tid = threadIdx.x;
    const int b  = blockIdx.x >> 5;
    const int t0 = (blockIdx.x & 31) << 6;
    const int w = tid >> 6, l = tid & 63, g = l >> 4, r15 = l & 15;

    const float* xrow = x + ((size_t)(b * TT + t0 + w * 16 + r15)) * FD;

    f32x4 acc[8] = {};

    #pragma unroll
    for (int m = 0; m < 4; ++m) {
        const int koff = m * 32 + g * 8;
        float4 xa = *reinterpret_cast<const float4*>(xrow + koff);
        float4 xb = *reinterpret_cast<const float4*>(xrow + koff + 4);
        short8 af;
        af[0] = (short)f2bf(xa.x); af[1] = (short)f2bf(xa.y);
        af[2] = (short)f2bf(xa.z); af[3] = (short)f2bf(xa.w);
        af[4] = (short)f2bf(xb.x); af[5] = (short)f2bf(xb.y);
        af[6] = (short)f2bf(xb.z); af[7] = (short)f2bf(xb.w);
        #pragma unroll
        for (int n = 0; n < 8; ++n) {
            short8 bfr = *reinterpret_cast<const short8*>(WT + (n * 16 + r15) * FD + koff);
            acc[n] = __builtin_amdgcn_mfma_f32_16x16x32_bf16(af, bfr, acc[n], 0, 0, 0);
        }
    }

    // s1/s2 from fp32 accumulators: lane holds h[t0+w*16+4g+r][16n+r15]
    float p1[4] = {0.f, 0.f, 0.f, 0.f}, p2[4] = {0.f, 0.f, 0.f, 0.f};
    #pragma unroll
    for (int n = 0; n < 8; ++n) {
        float a1v = a[n * 16 + r15];
        float a2v = a[FD + n * 16 + r15];
        #pragma unroll
        for (int r = 0; r < 4; ++r) {
            p1[r] += acc[n][r] * a1v;
            p2[r] += acc[n][r] * a2v;
        }
    }
    #pragma unroll
    for (int r = 0; r < 4; ++r) {
        #pragma unroll
        for (int off = 8; off >= 1; off >>= 1) {
            p1[r] += __shfl_xor(p1[r], off);
            p2[r] += __shfl_xor(p2[r], off);
        }
    }
    if (r15 == 0) {
        const int trow = t0 + w * 16 + g * 4;
        #pragma unroll
        for (int r = 0; r < 4; ++r) {
            s1[b * TT + trow + r] = p1[r];
            s2[b * TT + trow + r] = p2[r];
        }
    }

    // stage h tile (bf16) transposed: hs[f][t_local]
    #pragma unroll
    for (int n = 0; n < 8; ++n)
        #pragma unroll
        for (int r = 0; r < 4; ++r)
            hs[n * 16 + r15][w * 16 + g * 4 + r] = f2bf(acc[n][r]);
    __syncthreads();

    // write fragment-linear hF: 4 j16-tiles x 4 n32 x 64 lanes x 16B = 16KB
    #pragma unroll
    for (int it = 0; it < 4; ++it) {
        int idx = it * 256 + tid;            // 0..1023
        int lp = idx & 63;                   // consumer lane
        int frag = idx >> 6;                 // 0..15
        int n32 = frag & 3, tl = frag >> 2;  // local j16 tile
        int fsrc = n32 * 32 + (lp & 31);
        int tsrc = tl * 16 + (lp >> 5) * 8;
        short8 v = *reinterpret_cast<const short8*>(&hs[fsrc][tsrc]);
        *reinterpret_cast<short8*>(
            hF + (((size_t)(b * 128 + (t0 >> 4) + tl)) * 4 + n32) * 512 + lp * 8) = v;
    }
}

// Kernel 2: fused mask+softmax+PV, barrier-free main loop (R9-proven).
// Block = 32 i-rows, 4 waves each owning a 512-j quarter x full f=128.
// mfma_f32_32x32x16_bf16: A = P[32i x 16j] built in registers from bitmask+s2;
// B = 1KB coalesced fragment loads from hF (L2), depth-1 register dbuf.
// All k_att inputs (bm 8MB + hF 8MB + s2) are L2/L3-resident — no streaming
// pollutant (the reason two-pass beats single-pass here).
__global__ __launch_bounds__(256, 4) void k_att(const unsigned char* __restrict__ bm,
                                                const unsigned short* __restrict__ hF,
                                                const float* __restrict__ s1,
                                                const float* __restrict__ s2,
                                                float* __restrict__ out)
{
    __shared__ __align__(16) float red[2][32][132];   // 33.8 KB
    __shared__ float dsum[4][32];

    const int tid = threadIdx.x;
    // bijective XCD swizzle: 1024 blocks = 8 XCDs x 128 contiguous
    const int wg = (blockIdx.x & 7) * 128 + (blockIdx.x >> 3);
    const int b  = wg >> 6;
    const int i0 = (wg & 63) << 5;
    const int w = tid >> 6, l = tid & 63;
    const int il = l & 31, h = l >> 5;        // A row, k-half
    const int hsh = h * 8;

    const int jbeg = w * (TT / 4);
    const float s1v = s1[b * TT + i0 + il];
    const float* s2p = s2 + b * TT + jbeg + h * 8;
    const unsigned char* bmrow = bm + ((size_t)(b * TT + i0 + il)) * 256 + w * 64;
    const unsigned short* hfp = hF + ((size_t)(b * 128 + (jbeg >> 4))) * 4 * 512 + l * 8;

    f32x16 acc[4] = {};
    float rsum = 0.f;

    short8 bb[2][4];                          // depth-1 B double-buffer
    #pragma unroll
    for (int n = 0; n < 4; ++n)
        bb[0][n] = *reinterpret_cast<const short8*>(hfp + (size_t)n * 512);

    uint4 bq;

    #pragma unroll
    for (int t = 0; t < 32; ++t) {            // 16 j per step
        const int cur = t & 1;
        if (t < 31) {                         // prefetch next step's B frags
            #pragma unroll
            for (int n = 0; n < 4; ++n)
                bb[cur ^ 1][n] = *reinterpret_cast<const short8*>(
                    hfp + (size_t)((t + 1) * 4 + n) * 512);
        }
        if ((t & 7) == 0)                     // bitmask: 16B covers 8 steps
            bq = *reinterpret_cast<const uint4*>(bmrow + (t >> 3) * 16);
        const int wi = (t & 7) >> 1;          // static word select
        const unsigned wsel = wi == 0 ? bq.x : wi == 1 ? bq.y : wi == 2 ? bq.z : bq.w;
        const unsigned bits = (wsel >> ((t & 1) * 16 + hsh)) & 0xffu;

        float4 sa = *reinterpret_cast<const float4*>(s2p + t * 16);
        float4 sb = *reinterpret_cast<const float4*>(s2p + t * 16 + 4);
        float csf[8] = {sa.x, sa.y, sa.z, sa.w, sb.x, sb.y, sb.z, sb.w};
        float pv[8];
        #pragma unroll
        for (int e = 0; e < 8; ++e) {
            float s = s1v + csf[e];
            s = fmaxf(s, ALPHA * s);                     // leaky_relu
            float p = ((int)(bits << (31 - e)) < 0) ? __expf(s) : 0.f;  // sign-bit mask
            rsum += p;                                   // denom (unrounded)
            pv[e] = p;
        }
        short8 af;
        #pragma unroll
        for (int e = 0; e < 8; ++e)
            af[e] = (short)bfbits(pv[e]);                // HW RNE cvt
        #pragma unroll
        for (int n = 0; n < 4; ++n)
            acc[n] = __builtin_amdgcn_mfma_f32_32x32x16_bf16(af, bb[cur][n], acc[n], 0, 0, 0);
    }

    // quarter row-sums: combine the two k-halves, store per-wave partials
    rsum += __shfl_xor(rsum, 32);
    if (l < 32) dsum[w][l] = rsum;

    // two-step LDS reduction of the 4 wave-partial accumulators
    if (w < 2) {
        #pragma unroll
        for (int n = 0; n < 4; ++n)
            #pragma unroll
            for (int r = 0; r < 16; ++r) {
                int irow = (r & 3) + 8 * (r >> 2) + 4 * h;
                red[w][irow][n * 32 + il] = acc[n][r];
            }
    }
    __syncthreads();
    if (w >= 2) {
        #pragma unroll
        for (int n = 0; n < 4; ++n)
            #pragma unroll
            for (int r = 0; r < 16; ++r) {
                int irow = (r & 3) + 8 * (r >> 2) + 4 * h;
                red[w - 2][irow][n * 32 + il] += acc[n][r];
            }
    }
    __syncthreads();

    // epilogue: 32 rows x 128 cols = 1024 float4 over 256 threads
    #pragma unroll
    for (int it = 0; it < 4; ++it) {
        int e = it * 256 + tid;
        int row = e >> 5;
        int c4 = (e & 31) << 2;
        float4 v0 = *reinterpret_cast<const float4*>(&red[0][row][c4]);
        float4 v1 = *reinterpret_cast<const float4*>(&red[1][row][c4]);
        float dn = dsum[0][row] + dsum[1][row] + dsum[2][row] + dsum[3][row];
        float ri = 1.0f / dn;
        float4 o;
        o.x = (v0.x + v1.x) * ri;
        o.y = (v0.y + v1.y) * ri;
        o.z = (v0.z + v1.z) * ri;
        o.w = (v0.w + v1.w) * ri;
        *reinterpret_cast<float4*>(out + ((size_t)(b * TT + i0 + row)) * FD + c4) = o;
    }
}

extern "C" void kernel_launch(void* const* d_in, const int* in_sizes, int n_in,
                              void* d_out, int out_size, void* d_ws, size_t ws_size,
                              hipStream_t stream)
{
    const float* x  = (const float*)d_in[0];
    const int* adj  = (const int*)d_in[1];
    const float* W  = (const float*)d_in[2];
    const float* a  = (const float*)d_in[3];
    float* out = (float*)d_out;

    unsigned short* hF = (unsigned short*)d_ws;                       // 8 MB bf16 (fragment-linear)
    float* s1 = (float*)((char*)d_ws + (size_t)NB * FD * TT * 2);
    float* s2 = s1 + NB * TT;
    unsigned short* WT = (unsigned short*)(s2 + NB * TT);             // 32 KB
    unsigned char* bm = (unsigned char*)(WT + FD * FD);               // 8 MB bitmask

    k_wt  <<<16, 256, 0, stream>>>(W, WT);
    k_h   <<<NB * (TT / 64), 256, 0, stream>>>(x, WT, a, hF, s1, s2);
    k_pack<<<NB * TT / 4, 256, 0, stream>>>(adj, bm);
    k_att <<<NB * (TT / 32), 256, 0, stream>>>(bm, hF, s1, s2, out);
}